// Round 1
// baseline (289.286 us; speedup 1.0000x reference)
//
#include <hip/hip_runtime.h>

typedef unsigned short u16;
typedef short bf16x8 __attribute__((ext_vector_type(8)));
typedef float f32x4 __attribute__((ext_vector_type(4)));

#define S_LEN 4096
#define NHEADS 16
#define NKVH 4
#define HDIM 128
#define HID 2048
#define NQKV 3072

__device__ __forceinline__ u16 f2bf(float x) {
  union { float f; unsigned u; } v; v.f = x;
  unsigned r = v.u + 0x7fffu + ((v.u >> 16) & 1u);
  return (u16)(r >> 16);
}
__device__ __forceinline__ float bf2f(u16 x) {
  union { unsigned u; float f; } v; v.u = ((unsigned)x) << 16;
  return v.f;
}
// async global->LDS, 16B per lane; lds ptr must be wave-uniform, data lands at base + lane*16
__device__ __forceinline__ void async16(u16* lds, const u16* g) {
  __builtin_amdgcn_global_load_lds((const __attribute__((address_space(1))) void*)g,
                                   (__attribute__((address_space(3))) void*)lds, 16, 0, 0);
}

// ---------------- cast fp32 -> bf16, vectorized ----------------
__global__ __launch_bounds__(256) void cast_f32_bf16(const float* __restrict__ in,
                                                     u16* __restrict__ out, int n4) {
  int i = blockIdx.x * 256 + threadIdx.x;
  if (i >= n4) return;
  float4 v = ((const float4*)in)[i];
  ushort4 o;
  o.x = f2bf(v.x); o.y = f2bf(v.y); o.z = f2bf(v.z); o.w = f2bf(v.w);
  ((ushort4*)out)[i] = o;
}

// ---------------- GEMM: C[M][N] = A[M][K] * B[N][K]^T, bf16 in, fp32 acc ----------------
// 128x128 tile, BK=64, 4 waves each 64x64, 16x16x32 mfma.
// LDS layout: 16B chunks, slot = m*8 + (c ^ (m&7))  (c = k-chunk 0..7) -> conflict-free b128 frag reads.
template<bool OUT_BF16>
__global__ __launch_bounds__(256) void gemm_bt(const u16* __restrict__ A, const u16* __restrict__ B,
                                               void* __restrict__ Cp, int M, int N, int K) {
  __shared__ __align__(16) u16 As[128 * 64];
  __shared__ __align__(16) u16 Bs[128 * 64];
  const int tid = threadIdx.x;
  const int w = tid >> 6, l = tid & 63;
  const int quad = l >> 4, l16 = l & 15;
  const int bm = blockIdx.x, bn = blockIdx.y;
  const int wr = w & 1, wc = w >> 1;

  const size_t abase = (size_t)bm * 128 * K;
  const size_t bbase = (size_t)bn * 128 * K;

  f32x4 acc[4][4];
  for (int i = 0; i < 4; ++i)
    for (int j = 0; j < 4; ++j) acc[i][j] = f32x4{0.f, 0.f, 0.f, 0.f};

  int sm[4], sc[4];
  for (int j = 0; j < 4; ++j) {
    int slot = (w * 4 + j) * 64 + l;
    sm[j] = slot >> 3;
    sc[j] = (slot & 7) ^ (sm[j] & 7);
  }
  int aoff[2][4], boff[2][4];
  for (int ksi = 0; ksi < 2; ++ksi) {
    int cb = ksi * 4 + quad;
    for (int mt = 0; mt < 4; ++mt) {
      int m = wr * 64 + mt * 16 + l16;
      aoff[ksi][mt] = (m * 8 + (cb ^ (m & 7))) * 8;
      int n = wc * 64 + mt * 16 + l16;
      boff[ksi][mt] = (n * 8 + (cb ^ (n & 7))) * 8;
    }
  }

  for (int kt = 0; kt < K; kt += 64) {
    __syncthreads();
    for (int j = 0; j < 4; ++j) {
      async16(&As[(w * 4 + j) * 64 * 8], A + abase + (size_t)sm[j] * K + kt + sc[j] * 8);
      async16(&Bs[(w * 4 + j) * 64 * 8], B + bbase + (size_t)sm[j] * K + kt + sc[j] * 8);
    }
    __syncthreads();
    for (int ksi = 0; ksi < 2; ++ksi) {
      bf16x8 af[4], bv[4];
      for (int mt = 0; mt < 4; ++mt) {
        af[mt] = *(const bf16x8*)&As[aoff[ksi][mt]];
        bv[mt] = *(const bf16x8*)&Bs[boff[ksi][mt]];
      }
      for (int mt = 0; mt < 4; ++mt)
        for (int nt = 0; nt < 4; ++nt)
          acc[mt][nt] = __builtin_amdgcn_mfma_f32_16x16x32_bf16(af[mt], bv[nt], acc[mt][nt], 0, 0, 0);
    }
  }

  const int row_base = bm * 128 + wr * 64;
  const int col_base = bn * 128 + wc * 64;
  for (int mt = 0; mt < 4; ++mt)
    for (int nt = 0; nt < 4; ++nt) {
      int col = col_base + nt * 16 + l16;
      for (int r = 0; r < 4; ++r) {
        int row = row_base + mt * 16 + quad * 4 + r;
        float v = acc[mt][nt][r];
        if (OUT_BF16) ((u16*)Cp)[(size_t)row * N + col] = f2bf(v);
        else          ((float*)Cp)[(size_t)row * N + col] = v;
      }
    }
}

// ---------------- RoPE + scatter q,k into [head][s][d] layouts ----------------
__global__ __launch_bounds__(256) void rope_scatter(const u16* __restrict__ qkv,
                                                    const float* __restrict__ cosp,
                                                    const float* __restrict__ sinp,
                                                    u16* __restrict__ Q, u16* __restrict__ Kd) {
  int idx = blockIdx.x * 256 + threadIdx.x;  // total 4096*20*64
  int d = idx & 63;
  int hh = (idx >> 6) % 20;
  int s = idx / (20 * 64);
  size_t base = (size_t)s * NQKV + hh * 128;
  float x1 = bf2f(qkv[base + d]);
  float x2 = bf2f(qkv[base + d + 64]);
  float c1 = cosp[s * 128 + d], s1 = sinp[s * 128 + d];
  float c2 = cosp[s * 128 + d + 64], s2 = sinp[s * 128 + d + 64];
  float o1 = x1 * c1 - x2 * s1;
  float o2 = x2 * c2 + x1 * s2;
  u16* dst = (hh < NHEADS) ? (Q + ((size_t)hh * S_LEN + s) * HDIM)
                           : (Kd + ((size_t)(hh - NHEADS) * S_LEN + s) * HDIM);
  dst[d] = f2bf(o1);
  dst[d + 64] = f2bf(o2);
}

// ---------------- V transpose: qkv[s][2560+j] -> Vt[j][s]  (j = kv*128+d) ----------------
__global__ __launch_bounds__(256) void vtrans(const u16* __restrict__ qkv, u16* __restrict__ Vt) {
  __shared__ u16 tile[64][65];
  int s0 = blockIdx.x * 64;
  int j0 = blockIdx.y * 64;
  int tid = threadIdx.x;
  for (int it = 0; it < 16; ++it) {
    int lin = it * 256 + tid;
    int sr = lin >> 6, jc = lin & 63;
    tile[sr][jc] = qkv[(size_t)(s0 + sr) * NQKV + 2560 + j0 + jc];
  }
  __syncthreads();
  for (int it = 0; it < 16; ++it) {
    int lin = it * 256 + tid;
    int dr = lin >> 6, sc = lin & 63;
    Vt[(size_t)(j0 + dr) * S_LEN + s0 + sc] = tile[sc][dr];
  }
}

// ---------------- block-sparse flash attention ----------------
// grid (64 qblocks, 16 heads), 256 thr. Wave w owns q rows w*16..w*16+15.
__global__ __launch_bounds__(256) void attn_kernel(const u16* __restrict__ Q, const u16* __restrict__ K,
                                                   const u16* __restrict__ Vt, u16* __restrict__ Aout) {
  const float SCALE = 0.08838834764831845f;
  const float NEGF = -3.0e38f;
  const int t = blockIdx.x, h = blockIdx.y;
  const int kvh = h >> 2;
  const int tid = threadIdx.x;
  const int w = tid >> 6, l = tid & 63, quad = l >> 4, l16 = l & 15;

  __shared__ __align__(16) u16 Qs[64 * 128];  // slot = m*16 + (c ^ (m&15))
  __shared__ __align__(16) u16 Ks[64 * 128];
  __shared__ __align__(16) u16 Vs[128 * 64];  // [d][s], slot = d*8 + (c ^ (d&7))
  __shared__ __align__(16) u16 Ps[4 * 16 * 72];  // per-wave 16 rows, pad to 72

  int sel[7]; int nsel = 0;
  {
    int g1 = (t >> 2) << 2, g0 = g1 - 4;
    int lo = t - 4; if (lo < 0) lo = 0;
    if (g0 >= 0 && g0 < lo) sel[nsel++] = g0;
    if (g1 < lo) sel[nsel++] = g1;
    for (int b = lo; b <= t; ++b) sel[nsel++] = b;
  }

  {
    const size_t qbase = ((size_t)h * S_LEN + t * 64) * HDIM;
    for (int j = 0; j < 4; ++j) {
      int slot = (w * 4 + j) * 64 + l;
      int m = slot >> 4;
      int c = (slot & 15) ^ (m & 15);
      async16(&Qs[(w * 4 + j) * 64 * 8], Q + qbase + m * 128 + c * 8);
    }
  }

  float m_run[4], l_run[4];
  for (int r = 0; r < 4; ++r) { m_run[r] = NEGF; l_run[r] = 0.f; }
  f32x4 oacc[8];
  for (int i = 0; i < 8; ++i) oacc[i] = f32x4{0.f, 0.f, 0.f, 0.f};

  for (int ib = 0; ib < nsel; ++ib) {
    const int kb = sel[ib];
    __syncthreads();
    {
      const size_t kbase = ((size_t)kvh * S_LEN + kb * 64) * HDIM;
      const size_t vbase = (size_t)kvh * HDIM * S_LEN + kb * 64;
      for (int j = 0; j < 4; ++j) {
        int slot = (w * 4 + j) * 64 + l;
        int mk = slot >> 4;
        int ck = (slot & 15) ^ (mk & 15);
        async16(&Ks[(w * 4 + j) * 64 * 8], K + kbase + mk * 128 + ck * 8);
        int dv = slot >> 3;
        int cv = (slot & 7) ^ (dv & 7);
        async16(&Vs[(w * 4 + j) * 64 * 8], Vt + vbase + (size_t)dv * S_LEN + cv * 8);
      }
    }
    __syncthreads();

    // S = Q K^T for this wave's 16 q rows x 64 key cols
    f32x4 sacc[4];
    for (int nt = 0; nt < 4; ++nt) sacc[nt] = f32x4{0.f, 0.f, 0.f, 0.f};
    const int mq = w * 16 + l16;
    for (int ks = 0; ks < 128; ks += 32) {
      int cb = (ks >> 3) + quad;
      bf16x8 af = *(const bf16x8*)&Qs[(mq * 16 + (cb ^ (mq & 15))) * 8];
      for (int nt = 0; nt < 4; ++nt) {
        int n = nt * 16 + l16;
        bf16x8 bv = *(const bf16x8*)&Ks[(n * 16 + (cb ^ (n & 15))) * 8];
        sacc[nt] = __builtin_amdgcn_mfma_f32_16x16x32_bf16(af, bv, sacc[nt], 0, 0, 0);
      }
    }

    const bool diag = (kb == t);
    float alpha[4];
    for (int r = 0; r < 4; ++r) {
      int qrow = w * 16 + quad * 4 + r;
      float pv[4];
      float vmax = NEGF;
      for (int nt = 0; nt < 4; ++nt) {
        float v = sacc[nt][r] * SCALE;
        if (diag && (nt * 16 + l16) > qrow) v = NEGF;
        pv[nt] = v;
        vmax = fmaxf(vmax, v);
      }
      for (int off = 1; off < 16; off <<= 1) vmax = fmaxf(vmax, __shfl_xor(vmax, off));
      float mnew = fmaxf(m_run[r], vmax);
      alpha[r] = __expf(m_run[r] - mnew);
      m_run[r] = mnew;
      float sum = 0.f;
      for (int nt = 0; nt < 4; ++nt) {
        float p = __expf(pv[nt] - mnew);
        sum += p;
        Ps[(w * 16 + quad * 4 + r) * 72 + nt * 16 + l16] = f2bf(p);
      }
      for (int off = 1; off < 16; off <<= 1) sum += __shfl_xor(sum, off);
      l_run[r] = l_run[r] * alpha[r] + sum;
    }
    for (int nt = 0; nt < 8; ++nt) {
      f32x4 o = oacc[nt];
      o[0] *= alpha[0]; o[1] *= alpha[1]; o[2] *= alpha[2]; o[3] *= alpha[3];
      oacc[nt] = o;
    }

    // O += P V   (P from per-wave LDS region, A-operand layout; V^T from Vs)
    for (int ks = 0; ks < 64; ks += 32) {
      bf16x8 pf = *(const bf16x8*)&Ps[(w * 16 + l16) * 72 + ks + quad * 8];
      int cb = (ks >> 3) + quad;
      for (int nt = 0; nt < 8; ++nt) {
        int n = nt * 16 + l16;
        bf16x8 vv = *(const bf16x8*)&Vs[(n * 8 + (cb ^ (n & 7))) * 8];
        oacc[nt] = __builtin_amdgcn_mfma_f32_16x16x32_bf16(pf, vv, oacc[nt], 0, 0, 0);
      }
    }
  }

  float inv[4];
  for (int r = 0; r < 4; ++r) inv[r] = 1.f / l_run[r];
  const int srow = t * 64 + w * 16 + quad * 4;
  for (int nt = 0; nt < 8; ++nt) {
    int col = h * 128 + nt * 16 + l16;
    for (int r = 0; r < 4; ++r)
      Aout[(size_t)(srow + r) * HID + col] = f2bf(oacc[nt][r] * inv[r]);
  }
}

extern "C" void kernel_launch(void* const* d_in, const int* in_sizes, int n_in,
                              void* d_out, int out_size, void* d_ws, size_t ws_size,
                              hipStream_t stream) {
  const float* hs   = (const float*)d_in[0];
  const float* cosp = (const float*)d_in[1];
  const float* sinp = (const float*)d_in[2];
  const float* wq   = (const float*)d_in[3];
  const float* wk   = (const float*)d_in[4];
  const float* wv   = (const float*)d_in[5];
  const float* wo   = (const float*)d_in[6];

  u16* hsb = (u16*)d_ws;                        // 4096*2048
  u16* W   = hsb + (size_t)S_LEN * HID;         // 3072*2048 (wq;wk;wv)
  u16* wob = W + (size_t)NQKV * HID;            // 2048*2048
  u16* qkv = wob + (size_t)HID * HID;           // 4096*3072
  u16* Qm  = qkv + (size_t)S_LEN * NQKV;        // 16*4096*128
  u16* Km  = Qm + (size_t)NHEADS * S_LEN * HDIM; // 4*4096*128
  u16* Vt  = Km + (size_t)NKVH * S_LEN * HDIM;  // 4*128*4096
  u16* att = Vt + (size_t)NKVH * HDIM * S_LEN;  // 4096*2048

  cast_f32_bf16<<<8192, 256, 0, stream>>>(hs, hsb, 2097152);
  cast_f32_bf16<<<4096, 256, 0, stream>>>(wq, W, 1048576);
  cast_f32_bf16<<<1024, 256, 0, stream>>>(wk, W + (size_t)4194304, 262144);
  cast_f32_bf16<<<1024, 256, 0, stream>>>(wv, W + (size_t)5242880, 262144);
  cast_f32_bf16<<<4096, 256, 0, stream>>>(wo, wob, 1048576);

  gemm_bt<true><<<dim3(32, 24), 256, 0, stream>>>(hsb, W, (void*)qkv, 4096, 3072, 2048);
  rope_scatter<<<20480, 256, 0, stream>>>(qkv, cosp, sinp, Qm, Km);
  vtrans<<<dim3(64, 8), 256, 0, stream>>>(qkv, Vt);
  attn_kernel<<<dim3(64, 16), 256, 0, stream>>>(Qm, Km, Vt, att);
  gemm_bt<false><<<dim3(32, 16), 256, 0, stream>>>(att, wob, d_out, 4096, 2048, 2048);
}